// Round 1
// baseline (411.171 us; speedup 1.0000x reference)
//
#include <hip/hip_runtime.h>
#include <hip/hip_bf16.h>

// DMoN pooling, MI355X. B=8, N=4096, C=128, K=64.
// Pipeline:
//  k_assign : s = softmax(x@W+b) via fp16-split MFMA (f32-accurate); writes s (f32, d_out)
//             and packed S fragments (fp16 hi+lo) for the big GEMM.
//  k_big    : per (batch, 64-row tile): Y = adj @ S via mfma_f32_16x16x32_f16
//             (adj streamed global->VGPR, full-line coalesced, read exactly once);
//             deg = rowsum(adj) for free; epilogue folds oadj_part = S_tile^T @ Y_tile.
//  k_small  : partials of ss = S^T S and pooled = S^T X.
//  k_reduce : reduce partials; selu -> out features.
//  k_finalize / k_scalars: losses + normalized out_adj.
// All reductions deterministic (fixed-order partials, no FP atomics).

typedef _Float16 f16x8 __attribute__((ext_vector_type(8)));
typedef float f32x4 __attribute__((ext_vector_type(4)));

#define MFMA16(a, b, c) __builtin_amdgcn_mfma_f32_16x16x32_f16((a), (b), (c), 0, 0, 0)

__device__ __forceinline__ void gld_lds16(const void* g, void* l) {
  __builtin_amdgcn_global_load_lds(
      (const __attribute__((address_space(1))) void*)g,
      (__attribute__((address_space(3))) void*)l, 16, 0, 0);
}

// Stage NCHUNK*4KB contiguous global -> contiguous LDS with 256 threads.
template <int NCHUNK>
__device__ __forceinline__ void stage_lds(const void* g, void* lbase, int tid) {
  char* ld = (char*)lbase + (tid >> 6) * 1024;   // wave-uniform base; HW adds lane*16
  const char* gs = (const char*)g + tid * 16;    // per-lane global source
#pragma unroll
  for (int p = 0; p < NCHUNK; ++p)
    gld_lds16(gs + p * 4096, ld + p * 4096);
}

// ---------------------------------------------------------------- k_assign
// grid 512 (b = blockIdx&7, tile = blockIdx>>3), block 256.
__global__ __launch_bounds__(256) void k_assign(
    const float* __restrict__ x, const float* __restrict__ w,
    const float* __restrict__ bias, float* __restrict__ s_out,
    _Float16* __restrict__ sB) {
  __shared__ __align__(16) _Float16 wT[2][64][136];  // [hi/lo][k][c], padded
  __shared__ __align__(16) float sT[64][76];         // s transposed [k][row], padded
  const int b = blockIdx.x & 7;
  const int it = blockIdx.x >> 3;
  const int n_base = it * 64;
  const int tid = threadIdx.x;

  for (int idx = tid; idx < 8192; idx += 256) {
    int c = idx >> 6, k = idx & 63;
    float v = w[idx];
    _Float16 h = (_Float16)v;
    wT[0][k][c] = h;
    wT[1][k][c] = (_Float16)(v - (float)h);
  }
  const int l = tid & 63, wv = tid >> 6;
  const int l15 = l & 15, g = l >> 4;
  float bv[4];
#pragma unroll
  for (int ct = 0; ct < 4; ++ct) bv[ct] = bias[ct * 16 + l15];
  __syncthreads();

  f32x4 acc[4];
#pragma unroll
  for (int ct = 0; ct < 4; ++ct) acc[ct] = (f32x4){bv[ct], bv[ct], bv[ct], bv[ct]};

  const float* xrow = x + ((size_t)(b * 4096 + n_base + wv * 16 + l15)) * 128;
#pragma unroll
  for (int cs = 0; cs < 4; ++cs) {
    const int c0 = cs * 32;
    f32x4 r0 = *(const f32x4*)(xrow + c0 + 8 * g);
    f32x4 r1 = *(const f32x4*)(xrow + c0 + 8 * g + 4);
    f16x8 ah, al;
#pragma unroll
    for (int j = 0; j < 4; ++j) {
      float v0 = r0[j]; _Float16 h0 = (_Float16)v0;
      ah[j] = h0; al[j] = (_Float16)(v0 - (float)h0);
      float v1 = r1[j]; _Float16 h1 = (_Float16)v1;
      ah[4 + j] = h1; al[4 + j] = (_Float16)(v1 - (float)h1);
    }
#pragma unroll
    for (int ct = 0; ct < 4; ++ct) {
      f16x8 bh = *(const f16x8*)&wT[0][ct * 16 + l15][c0 + 8 * g];
      f16x8 bl = *(const f16x8*)&wT[1][ct * 16 + l15][c0 + 8 * g];
      acc[ct] = MFMA16(ah, bh, acc[ct]);
      acc[ct] = MFMA16(al, bh, acc[ct]);
      acc[ct] = MFMA16(ah, bl, acc[ct]);
    }
  }

  // softmax over K=64 per row; row r lives in 16 lanes (same g), 4 regs (ct).
#pragma unroll
  for (int r = 0; r < 4; ++r) {
    float m = fmaxf(fmaxf(acc[0][r], acc[1][r]), fmaxf(acc[2][r], acc[3][r]));
#pragma unroll
    for (int off = 1; off < 16; off <<= 1) m = fmaxf(m, __shfl_xor(m, off, 64));
    float e[4], sum = 0.f;
#pragma unroll
    for (int ct = 0; ct < 4; ++ct) { e[ct] = __expf(acc[ct][r] - m); sum += e[ct]; }
#pragma unroll
    for (int off = 1; off < 16; off <<= 1) sum += __shfl_xor(sum, off, 64);
    float inv = 1.0f / sum;
#pragma unroll
    for (int ct = 0; ct < 4; ++ct) acc[ct][r] = e[ct] * inv;
  }

  const int row_l = wv * 16 + 4 * g;
  float* srow = s_out + ((size_t)(b * 4096 + n_base)) * 64;
#pragma unroll
  for (int r = 0; r < 4; ++r)
#pragma unroll
    for (int ct = 0; ct < 4; ++ct) {
      srow[(size_t)(row_l + r) * 64 + ct * 16 + l15] = acc[ct][r];
      sT[ct * 16 + l15][row_l + r] = acc[ct][r];
    }
  __syncthreads();

  // repack to B-fragment layout: [hl][ks][ct][lane][8] fp16
  _Float16* dst = sB + (size_t)(b * 64 + it) * 8192;
#pragma unroll
  for (int p = 0; p < 4; ++p) {
    int slot = tid + 256 * p;
    int hl = slot >> 9, ks = (slot >> 8) & 1, ct = (slot >> 6) & 3, ln = slot & 63;
    int col = ct * 16 + (ln & 15);
    int row0 = ks * 32 + 8 * (ln >> 4);
    f16x8 o;
#pragma unroll
    for (int j = 0; j < 8; ++j) {
      float v = sT[col][row0 + j];
      _Float16 h = (_Float16)v;
      o[j] = hl ? (_Float16)(v - (float)h) : h;
    }
    *(f16x8*)(dst + slot * 8) = o;
  }
}

// ---------------------------------------------------------------- k_big
// grid 512 (b = blockIdx&7 -> XCD pin, nt = blockIdx>>3), block 256.
__global__ __launch_bounds__(256) void k_big(
    const float* __restrict__ adj, const _Float16* __restrict__ sB,
    const float* __restrict__ s_out, float* __restrict__ deg,
    float* __restrict__ oadj_part) {
  __shared__ __align__(16) char pool[49152];
  float* Yl = (float*)pool;               // aliases sB buf0 (used after loop)
  float* sl = (float*)(pool + 32768);
  const int b = blockIdx.x & 7;
  const int nt = blockIdx.x >> 3;
  const int n_base = nt * 64;
  const int tid = threadIdx.x;
  const int l = tid & 63, wv = tid >> 6;
  const int l15 = l & 15, g = l >> 4;

  const char* sBb = (const char*)(sB + (size_t)b * 64 * 8192);
  const float* arow = adj + ((size_t)b * 4096 + n_base + wv * 16 + l15) * 4096;

  // prologue: stage s tile (f32, for fold) + sB iter0 + first raw adj
  stage_lds<4>(s_out + ((size_t)(b * 4096 + n_base)) * 64, sl, tid);
  stage_lds<4>(sBb, pool, tid);
  f32x4 c0 = *(const f32x4*)(arow + 8 * g);
  f32x4 c1 = *(const f32x4*)(arow + 8 * g + 4);
  f32x4 c2 = *(const f32x4*)(arow + 32 + 8 * g);
  f32x4 c3 = *(const f32x4*)(arow + 32 + 8 * g + 4);
  f32x4 n0 = {}, n1 = {}, n2 = {}, n3 = {};
  __syncthreads();

  f32x4 acc[4] = {};
  float dacc = 0.f;
  for (int itr = 0; itr < 64; ++itr) {
    const int buf = itr & 1;
    if (itr < 63) {
      stage_lds<4>(sBb + (size_t)(itr + 1) * 16384, pool + (buf ^ 1) * 16384, tid);
      const float* an = arow + (itr + 1) * 64 + 8 * g;
      n0 = *(const f32x4*)(an);
      n1 = *(const f32x4*)(an + 4);
      n2 = *(const f32x4*)(an + 32);
      n3 = *(const f32x4*)(an + 36);
    }
    dacc += c0[0] + c0[1] + c0[2] + c0[3] + c1[0] + c1[1] + c1[2] + c1[3] +
            c2[0] + c2[1] + c2[2] + c2[3] + c3[0] + c3[1] + c3[2] + c3[3];
    f16x8 a0, a1;
#pragma unroll
    for (int j = 0; j < 4; ++j) {
      a0[j] = (_Float16)c0[j]; a0[4 + j] = (_Float16)c1[j];
      a1[j] = (_Float16)c2[j]; a1[4 + j] = (_Float16)c3[j];
    }
    const f16x8* fb = (const f16x8*)(pool + buf * 16384);
#pragma unroll
    for (int ct = 0; ct < 4; ++ct) {
      f16x8 bh0 = fb[(0 + ct) * 64 + l];
      f16x8 bh1 = fb[(4 + ct) * 64 + l];
      f16x8 bl0 = fb[(8 + ct) * 64 + l];
      f16x8 bl1 = fb[(12 + ct) * 64 + l];
      acc[ct] = MFMA16(a0, bh0, acc[ct]);
      acc[ct] = MFMA16(a0, bl0, acc[ct]);
      acc[ct] = MFMA16(a1, bh1, acc[ct]);
      acc[ct] = MFMA16(a1, bl1, acc[ct]);
    }
    __syncthreads();  // drains vmcnt; next iter's buf is staged, prev reads done
    c0 = n0; c1 = n1; c2 = n2; c3 = n3;
  }

  // deg (rowsum of adj), deterministic
  dacc += __shfl_xor(dacc, 16, 64);
  dacc += __shfl_xor(dacc, 32, 64);
  if (l < 16) deg[b * 4096 + n_base + wv * 16 + l] = dacc;

  // Y tile -> LDS (aliases dead sB buf0)
#pragma unroll
  for (int r = 0; r < 4; ++r)
#pragma unroll
    for (int ct = 0; ct < 4; ++ct)
      Yl[(wv * 16 + 4 * g + r) * 64 + ct * 16 + l15] = acc[ct][r];
  __syncthreads();

  // fold: oadj_part[b][nt] = S_tile^T @ Y_tile  (f32)
  const int kq = tid >> 4, lq = tid & 15;
  f32x4 a2[4] = {};
  for (int r = 0; r < 64; ++r) {
    f32x4 s4 = *(const f32x4*)(sl + r * 64 + kq * 4);
    f32x4 y4 = *(const f32x4*)(Yl + r * 64 + lq * 4);
#pragma unroll
    for (int i = 0; i < 4; ++i)
#pragma unroll
      for (int j = 0; j < 4; ++j) a2[i][j] += s4[i] * y4[j];
  }
  float* op = oadj_part + ((size_t)(b * 64 + nt)) * 4096;
#pragma unroll
  for (int i = 0; i < 4; ++i)
    *(f32x4*)(op + (kq * 4 + i) * 64 + lq * 4) = a2[i];
}

// ---------------------------------------------------------------- k_small
// partials of ss = S^T S and pooled = S^T X. grid 256 (b&7, chunk of 128 rows).
__global__ __launch_bounds__(256) void k_small(
    const float* __restrict__ s_out, const float* __restrict__ x,
    float* __restrict__ ss_part, float* __restrict__ p_part) {
  __shared__ __align__(16) float sc[32 * 64];
  __shared__ __align__(16) float xc[32 * 128];
  const int b = blockIdx.x & 7;
  const int ch = blockIdx.x >> 3;
  const int tid = threadIdx.x;
  const int kq = tid >> 4, cq = tid & 15;
  f32x4 ssa[4] = {};
  f32x4 pa[8] = {};
  for (int sub = 0; sub < 4; ++sub) {
    if (sub) __syncthreads();
    const int nb = ch * 128 + sub * 32;
    stage_lds<2>(s_out + ((size_t)(b * 4096 + nb)) * 64, sc, tid);
    stage_lds<4>(x + ((size_t)(b * 4096 + nb)) * 128, xc, tid);
    __syncthreads();
    for (int n = 0; n < 32; ++n) {
      f32x4 s4 = *(const f32x4*)(sc + n * 64 + kq * 4);
      f32x4 s4b = *(const f32x4*)(sc + n * 64 + cq * 4);
      f32x4 x4a = *(const f32x4*)(xc + n * 128 + cq * 8);
      f32x4 x4b = *(const f32x4*)(xc + n * 128 + cq * 8 + 4);
#pragma unroll
      for (int i = 0; i < 4; ++i) {
#pragma unroll
        for (int j = 0; j < 4; ++j) {
          ssa[i][j] += s4[i] * s4b[j];
          pa[i * 2][j] += s4[i] * x4a[j];
          pa[i * 2 + 1][j] += s4[i] * x4b[j];
        }
      }
    }
  }
  float* sp = ss_part + ((size_t)(b * 32 + ch)) * 4096;
  float* pp = p_part + ((size_t)(b * 32 + ch)) * 8192;
#pragma unroll
  for (int i = 0; i < 4; ++i) {
    *(f32x4*)(sp + (kq * 4 + i) * 64 + cq * 4) = ssa[i];
    *(f32x4*)(pp + (kq * 4 + i) * 128 + cq * 8) = pa[i * 2];
    *(f32x4*)(pp + (kq * 4 + i) * 128 + cq * 8 + 4) = pa[i * 2 + 1];
  }
}

// ---------------------------------------------------------------- k_reduce
__global__ __launch_bounds__(256) void k_reduce(
    const float* __restrict__ oadj_part, const float* __restrict__ ss_part,
    const float* __restrict__ p_part, float* __restrict__ oadj_raw,
    float* __restrict__ ss_sum, float* __restrict__ out_feat) {
  const int gid = blockIdx.x * 256 + threadIdx.x;
  if (gid < 32768) {
    int b = gid >> 12, e = gid & 4095;
    float s = 0.f;
    for (int t = 0; t < 64; ++t) s += oadj_part[((size_t)(b * 64 + t)) * 4096 + e];
    oadj_raw[gid] = s;
  } else if (gid < 65536) {
    int g2 = gid - 32768, b = g2 >> 12, e = g2 & 4095;
    float s = 0.f;
    for (int t = 0; t < 32; ++t) s += ss_part[((size_t)(b * 32 + t)) * 4096 + e];
    ss_sum[g2] = s;
  } else {
    int g3 = gid - 65536, b = g3 >> 13, e = g3 & 8191;
    float s = 0.f;
    for (int t = 0; t < 32; ++t) s += p_part[((size_t)(b * 32 + t)) * 8192 + e];
    const float scale = 1.0507009873554805f, alpha = 1.6732632423543772f;
    out_feat[g3] = s > 0.f ? scale * s : scale * alpha * (expf(s) - 1.f);
  }
}

// ---------------------------------------------------------------- k_finalize
__global__ __launch_bounds__(256) void k_finalize(
    const float* __restrict__ oadj_raw, const float* __restrict__ ss_sum,
    const float* __restrict__ deg, const float* __restrict__ s_out,
    float* __restrict__ out_adj, float* __restrict__ loss_part) {
  __shared__ float red[256];
  __shared__ float q1[4][64], q2[4][64];
  __shared__ float ca[64], dvec[64];
  __shared__ float sh_scalar;
  const int b = blockIdx.x, t = threadIdx.x;
  const float* degb = deg + b * 4096;
  const float* ob = oadj_raw + b * 4096;
  const float* ssb = ss_sum + b * 4096;

  // sm = sum(deg) == 2m
  float p = 0.f;
  for (int i = t; i < 4096; i += 256) p += degb[i];
  red[t] = p; __syncthreads();
  for (int o = 128; o > 0; o >>= 1) { if (t < o) red[t] += red[t + o]; __syncthreads(); }
  if (t == 0) sh_scalar = red[0];
  __syncthreads();
  const float sm = sh_scalar;
  __syncthreads();

  // csize, ca
  const int k = t & 63, q = t >> 6;
  const float* sb = s_out + (size_t)b * 4096 * 64;
  float cs = 0.f, cac = 0.f;
  for (int n = q; n < 4096; n += 4) {
    float sv = sb[(size_t)n * 64 + k];
    cs += sv; cac += sv * degb[n];
  }
  q1[q][k] = cs; q2[q][k] = cac;
  __syncthreads();
  float csize_k = 0.f;
  if (t < 64) {
    csize_k = q1[0][t] + q1[1][t] + q1[2][t] + q1[3][t];
    ca[t] = q2[0][t] + q2[1][t] + q2[2][t] + q2[3][t];
  }
  __syncthreads();

  // spectral: -(sum_k diag - ca^2/sm)/sm
  float tp = 0.f;
  if (t < 64) { float dg = ob[t * 64 + t]; tp = dg - ca[t] * ca[t] / sm; }
  red[t] = tp; __syncthreads();
  for (int o = 128; o > 0; o >>= 1) { if (t < o) red[t] += red[t + o]; __syncthreads(); }
  const float spectral_b = -red[0] / sm;
  __syncthreads();

  // ortho
  float fp = 0.f;
  for (int i = t; i < 4096; i += 256) { float v = ssb[i]; fp += v * v; }
  red[t] = fp; __syncthreads();
  for (int o = 128; o > 0; o >>= 1) { if (t < o) red[t] += red[t + o]; __syncthreads(); }
  const float fro = sqrtf(red[0]);
  __syncthreads();
  float op2 = 0.f;
  for (int i = t; i < 4096; i += 256) {
    float v = ssb[i] / fro - (((i >> 6) == (i & 63)) ? 0.125f : 0.f);
    op2 += v * v;
  }
  red[t] = op2; __syncthreads();
  for (int o = 128; o > 0; o >>= 1) { if (t < o) red[t] += red[t + o]; __syncthreads(); }
  const float ortho_b = sqrtf(red[0]);
  __syncthreads();

  // cluster
  red[t] = (t < 64) ? csize_k * csize_k : 0.f;
  __syncthreads();
  for (int o = 128; o > 0; o >>= 1) { if (t < o) red[t] += red[t + o]; __syncthreads(); }
  const float cluster_b = sqrtf(red[0]) * 8.f / 4096.f - 1.f;
  __syncthreads();

  // normalized out_adj (diag zeroed)
  float rp = 0.f;
  {
    const float* orow = ob + k * 64;
    for (int lc = q * 16; lc < q * 16 + 16; ++lc)
      if (lc != k) rp += orow[lc];
  }
  q1[q][k] = rp; __syncthreads();
  if (t < 64) dvec[t] = sqrtf(q1[0][t] + q1[1][t] + q1[2][t] + q1[3][t]) + 1e-15f;
  __syncthreads();
  for (int i = t; i < 4096; i += 256) {
    int kk = i >> 6, lc = i & 63;
    float v = (kk == lc) ? 0.f : ob[i] / (dvec[kk] * dvec[lc]);
    out_adj[(size_t)b * 4096 + i] = v;
  }
  if (t == 0) {
    loss_part[b * 3 + 0] = spectral_b;
    loss_part[b * 3 + 1] = ortho_b;
    loss_part[b * 3 + 2] = cluster_b;
  }
}

__global__ void k_scalars(const float* __restrict__ lp, float* __restrict__ o3) {
  if (threadIdx.x == 0) {
    float s = 0.f, o = 0.f, c = 0.f;
    for (int b = 0; b < 8; ++b) { s += lp[b * 3]; o += lp[b * 3 + 1]; c += lp[b * 3 + 2]; }
    o3[0] = s * 0.125f; o3[1] = o * 0.125f; o3[2] = c * 0.125f;
  }
}

extern "C" void kernel_launch(void* const* d_in, const int* in_sizes, int n_in,
                              void* d_out, int out_size, void* d_ws, size_t ws_size,
                              hipStream_t stream) {
  const float* x = (const float*)d_in[0];
  const float* adj = (const float*)d_in[1];
  const float* w = (const float*)d_in[2];
  const float* bias = (const float*)d_in[3];
  float* out = (float*)d_out;
  float* s_out = out;                       // [8,4096,64]
  float* out_feat = out + 2097152;          // [8,64,128]
  float* out_adj = out + 2162688;           // [8,64,64]
  float* out_sc = out + 2195456;            // 3 scalars

  char* ws = (char*)d_ws;
  _Float16* sB = (_Float16*)ws;                              // 8 MB
  float* oadj_part = (float*)(ws + (8u << 20));              // 8 MB
  float* ss_part = (float*)(ws + (16u << 20));               // 4 MB
  float* p_part = (float*)(ws + (20u << 20));                // 8 MB
  float* deg = (float*)(ws + (28u << 20));                   // 128 KB
  float* oadj_raw = (float*)(ws + (28u << 20) + (128u << 10));
  float* ss_sum = (float*)(ws + (28u << 20) + (256u << 10));
  float* loss_part = (float*)(ws + (28u << 20) + (384u << 10));

  k_assign<<<dim3(512), dim3(256), 0, stream>>>(x, w, bias, s_out, sB);
  k_big<<<dim3(512), dim3(256), 0, stream>>>(adj, sB, s_out, deg, oadj_part);
  k_small<<<dim3(256), dim3(256), 0, stream>>>(s_out, x, ss_part, p_part);
  k_reduce<<<dim3(512), dim3(256), 0, stream>>>(oadj_part, ss_part, p_part,
                                                oadj_raw, ss_sum, out_feat);
  k_finalize<<<dim3(8), dim3(256), 0, stream>>>(oadj_raw, ss_sum, deg, s_out,
                                                out_adj, loss_part);
  k_scalars<<<dim3(1), dim3(64), 0, stream>>>(loss_part, out_sc);
}